// Round 6
// baseline (746.346 us; speedup 1.0000x reference)
//
#include <hip/hip_runtime.h>
#include <hip/hip_fp16.h>

#define DI __device__ __forceinline__

typedef _Float16 f16x8 __attribute__((ext_vector_type(8)));
typedef float f32x4 __attribute__((ext_vector_type(4)));

struct alignas(8) h4 { __half x, y, z, w; };

DI void async16(const void* g, void* l) {
  __builtin_amdgcn_global_load_lds(
      (__attribute__((address_space(1))) void*)g,
      (__attribute__((address_space(3))) void*)l, 16, 0, 0);
}

DI float waveReduceSum(float v) {
#pragma unroll
  for (int i = 1; i < 64; i <<= 1) v += __shfl_xor(v, i);
  return v;
}
DI float waveReduceMax(float v) {
#pragma unroll
  for (int i = 1; i < 64; i <<= 1) v = fmaxf(v, __shfl_xor(v, i));
  return v;
}

DI float gelu_exact(float x) { return 0.5f * x * (1.f + erff(x * 0.70710678118654752f)); }

#define MFMA16(b_, a_, c_) __builtin_amdgcn_mfma_f32_16x16x32_f16((b_), (a_), (c_), 0, 0, 0)

// ---------------------------------------------------------------------------
// gemm_nt8 — m201-faithful 8-phase 256x256 schedule (learn_hip, 1563 TF @4k).
// BK=64, 512 threads (8 waves = 2M x 4N, wave-tile 128x64, acc[8][4]).
// Per K-tile: 4 phases = C-quadrants x full K:
//   P1: read a-lo(8)+b-lo(4) | stage (t+1).B1 | bar | lgkm0 | 16 MFMA al x bl | bar
//   P2: read a-hi(8)         | stage (t+1).A0 | bar | lgkm0 | 16 MFMA ah x bl | bar
//   P3: read b-hi(4)         | stage (t+1).A1 | bar | lgkm0 | 16 MFMA ah x bh | bar
//   P4: (a-lo held in regs)  | stage (t+2).B0 | vmcnt(2) | bar | 16 MFMA al x bh | bar
// Staging = half-tiles (128 rows x 64 k = 2 global_load_lds/thread), rolled so
// each slot is restaged >=1 barrier after its last reader (two-barrier phase
// envelope makes the t+1-slot restages WAR-safe vs slow waves' in-flight reads).
// vmcnt(2) once per K-tile publishes ALL of tile t+1 (only P4's own 2 loads may
// fly) -- counted, never drains in steady state. setprio(1) wraps each MFMA
// cluster (T5: +21-25% on 8-phase). XOR-chunk LDS layout (0 conflicts) kept;
// swapped-operand MFMA + packed float4/h4 epilogue (R5-verified) kept.
// ---------------------------------------------------------------------------
template <typename CT, bool BIAS, bool BROW>
__global__ __launch_bounds__(512, 2) void gemm_nt8(
    const __half* __restrict__ A, int lda, long long sA,
    const __half* __restrict__ Bt, int ldb, long long sB,
    const float* __restrict__ bias, long long sBias,
    CT* __restrict__ C, int ldc, long long sC,
    int nT, int K) {
  __shared__ __align__(16) __half As[2][16384];  // 2 bufs x (2 halves x 128 x 64)
  __shared__ __align__(16) __half Bs[2][16384];

  const int tid = threadIdx.x;
  const int wave = tid >> 6, lane = tid & 63;

  // GROUP_M=4 swizzled block decode (all mT here divisible by 4)
  const int gsz = 4 * nT;
  const int g = blockIdx.x / gsz, r = blockIdx.x % gsz;
  const int m0 = (g * 4 + (r & 3)) * 256;
  const int n0 = (r >> 2) * 256;

  A += (long long)blockIdx.z * sA;
  Bt += (long long)blockIdx.z * sB;
  C += (long long)blockIdx.z * sC;
  if constexpr (BIAS || BROW) bias += (long long)blockIdx.z * sBias;

  const int wm = wave >> 2, wn = wave & 3;

  f32x4 acc[8][4];
#pragma unroll
  for (int i = 0; i < 8; ++i)
#pragma unroll
    for (int j = 0; j < 4; ++j) acc[i][j] = (f32x4){0.f, 0.f, 0.f, 0.f};

  // staging: half h of tile t = rows h*128..h*128+127; 2 instrs of 64 rows.
  // thread t writes global (row = h*128 + i*64 + (t>>3), chunk (t&7)^(row&7))
  // to LDS linear (buf*32768 + h*16384 + i*8192 + tid*16) -- XOR-chunk layout.
  const int srow = tid >> 3;
  const int gc = (tid & 7) ^ (srow & 7);
  const __half* Ag = A + (size_t)(m0 + srow) * lda + gc * 8;
  const __half* Bg = Bt + (size_t)(n0 + srow) * ldb + gc * 8;
  const size_t a64 = (size_t)64 * lda, b64 = (size_t)64 * ldb;
  char* AsW = (char*)As + wave * 1024;
  char* BsW = (char*)Bs + wave * 1024;

#define STG_A(t, h)                                                       \
  {                                                                       \
    const __half* s_ = Ag + (size_t)(h) * 128 * lda + (t) * 64;           \
    char* d_ = AsW + (((t) & 1) ? 32768 : 0) + (h) * 16384;               \
    async16(s_, d_);                                                      \
    async16(s_ + a64, d_ + 8192);                                         \
  }
#define STG_B(t, h)                                                       \
  {                                                                       \
    const __half* s_ = Bg + (size_t)(h) * 128 * ldb + (t) * 64;           \
    char* d_ = BsW + (((t) & 1) ? 32768 : 0) + (h) * 16384;               \
    async16(s_, d_);                                                      \
    async16(s_ + b64, d_ + 8192);                                         \
  }

  // frag read bases: A row = wm*128 + mi*16 + ml (A-half wm); B row = wn*64 +
  // nj*16 + ml (B-half wn>>1). chunk byte co0 (ks0) / co0^64 (ks1).
  const int ml = lane & 15, q = lane >> 4, lx = lane & 7;
  const int co0 = (q ^ lx) * 16, co1 = co0 ^ 64;
  const char* Ar = (const char*)As + wm * 16384 + ml * 128;
  const char* Br = (const char*)Bs + (wn >> 1) * 16384 + (wn & 1) * 8192 + ml * 128;

  const int nt = K >> 6;
  // prologue: tile0 all 4 halves + tile1.B0; vmcnt(2) -> tile0 landed.
  STG_B(0, 0);
  STG_A(0, 0);
  STG_A(0, 1);
  STG_B(0, 1);
  if (nt > 1) {
    STG_B(1, 0);
    asm volatile("s_waitcnt vmcnt(2)" ::: "memory");
  } else {
    asm volatile("s_waitcnt vmcnt(0)" ::: "memory");
  }
  __builtin_amdgcn_s_barrier();

  f16x8 al0[4], al1[4], ah0[4], ah1[4];
  f16x8 bl0[2], bl1[2], bh0[2], bh1[2];

  for (int t = 0; t < nt; ++t) {
    const int pb = (t & 1) ? 32768 : 0;
    const char* Ap = Ar + pb;
    const char* Bp = Br + pb;

    // ---- P1: a-lo + b-lo reads; stage (t+1).B1 ----
#pragma unroll
    for (int i = 0; i < 4; ++i) {
      al0[i] = *(const f16x8*)(Ap + i * 2048 + co0);
      al1[i] = *(const f16x8*)(Ap + i * 2048 + co1);
    }
#pragma unroll
    for (int j = 0; j < 2; ++j) {
      bl0[j] = *(const f16x8*)(Bp + j * 2048 + co0);
      bl1[j] = *(const f16x8*)(Bp + j * 2048 + co1);
    }
    if (t + 1 < nt) STG_B(t + 1, 1);
    __builtin_amdgcn_s_barrier();
    asm volatile("s_waitcnt lgkmcnt(0)" ::: "memory");
    __builtin_amdgcn_sched_barrier(0);
    __builtin_amdgcn_s_setprio(1);
#pragma unroll
    for (int i = 0; i < 4; ++i)
#pragma unroll
      for (int j = 0; j < 2; ++j) acc[i][j] = MFMA16(bl0[j], al0[i], acc[i][j]);
#pragma unroll
    for (int i = 0; i < 4; ++i)
#pragma unroll
      for (int j = 0; j < 2; ++j) acc[i][j] = MFMA16(bl1[j], al1[i], acc[i][j]);
    __builtin_amdgcn_s_setprio(0);
    __builtin_amdgcn_s_barrier();

    // ---- P2: a-hi reads; stage (t+1).A0 ----
#pragma unroll
    for (int i = 0; i < 4; ++i) {
      ah0[i] = *(const f16x8*)(Ap + (4 + i) * 2048 + co0);
      ah1[i] = *(const f16x8*)(Ap + (4 + i) * 2048 + co1);
    }
    if (t + 1 < nt) STG_A(t + 1, 0);
    __builtin_amdgcn_s_barrier();
    asm volatile("s_waitcnt lgkmcnt(0)" ::: "memory");
    __builtin_amdgcn_sched_barrier(0);
    __builtin_amdgcn_s_setprio(1);
#pragma unroll
    for (int i = 0; i < 4; ++i)
#pragma unroll
      for (int j = 0; j < 2; ++j) acc[4 + i][j] = MFMA16(bl0[j], ah0[i], acc[4 + i][j]);
#pragma unroll
    for (int i = 0; i < 4; ++i)
#pragma unroll
      for (int j = 0; j < 2; ++j) acc[4 + i][j] = MFMA16(bl1[j], ah1[i], acc[4 + i][j]);
    __builtin_amdgcn_s_setprio(0);
    __builtin_amdgcn_s_barrier();

    // ---- P3: b-hi reads; stage (t+1).A1 ----
#pragma unroll
    for (int j = 0; j < 2; ++j) {
      bh0[j] = *(const f16x8*)(Bp + (2 + j) * 2048 + co0);
      bh1[j] = *(const f16x8*)(Bp + (2 + j) * 2048 + co1);
    }
    if (t + 1 < nt) STG_A(t + 1, 1);
    __builtin_amdgcn_s_barrier();
    asm volatile("s_waitcnt lgkmcnt(0)" ::: "memory");
    __builtin_amdgcn_sched_barrier(0);
    __builtin_amdgcn_s_setprio(1);
#pragma unroll
    for (int i = 0; i < 4; ++i)
#pragma unroll
      for (int j = 0; j < 2; ++j) acc[4 + i][2 + j] = MFMA16(bh0[j], ah0[i], acc[4 + i][2 + j]);
#pragma unroll
    for (int i = 0; i < 4; ++i)
#pragma unroll
      for (int j = 0; j < 2; ++j) acc[4 + i][2 + j] = MFMA16(bh1[j], ah1[i], acc[4 + i][2 + j]);
    __builtin_amdgcn_s_setprio(0);
    __builtin_amdgcn_s_barrier();

    // ---- P4: no reads (a-lo held); stage (t+2).B0; counted vmcnt publishes
    // ALL of tile t+1 (only P4's own 2 loads may remain in flight) ----
    if (t + 2 < nt) STG_B(t + 2, 0);
    asm volatile("s_waitcnt vmcnt(2)" ::: "memory");
    __builtin_amdgcn_s_barrier();
    __builtin_amdgcn_s_setprio(1);
#pragma unroll
    for (int i = 0; i < 4; ++i)
#pragma unroll
      for (int j = 0; j < 2; ++j) acc[i][2 + j] = MFMA16(bh0[j], al0[i], acc[i][2 + j]);
#pragma unroll
    for (int i = 0; i < 4; ++i)
#pragma unroll
      for (int j = 0; j < 2; ++j) acc[i][2 + j] = MFMA16(bh1[j], al1[i], acc[i][2 + j]);
    __builtin_amdgcn_s_setprio(0);
    __builtin_amdgcn_s_barrier();
  }
#undef STG_A
#undef STG_B

  // epilogue (swapped layout): frag (i,j) holds C[m0+wm*128+i*16+ml]
  // [n0+wn*64+j*16+q*4 + rr], rr=0..3 -> packed 8B/16B stores.
#pragma unroll
  for (int j = 0; j < 4; ++j) {
    const int col0 = n0 + wn * 64 + j * 16 + q * 4;
    float4 bc = {0.f, 0.f, 0.f, 0.f};
    if constexpr (BIAS) bc = *(const float4*)(bias + col0);
#pragma unroll
    for (int i = 0; i < 8; ++i) {
      const int row = m0 + wm * 128 + i * 16 + ml;
      const float br = BROW ? bias[row] : 0.f;
      const float v0 = acc[i][j][0] + bc.x + br;
      const float v1 = acc[i][j][1] + bc.y + br;
      const float v2 = acc[i][j][2] + bc.z + br;
      const float v3 = acc[i][j][3] + bc.w + br;
      if constexpr (sizeof(CT) == 4) {
        *(float4*)(C + (size_t)row * ldc + col0) = make_float4(v0, v1, v2, v3);
      } else {
        h4 o{__float2half(v0), __float2half(v1), __float2half(v2), __float2half(v3)};
        *(h4*)((__half*)C + (size_t)row * ldc + col0) = o;
      }
    }
  }
}

// ---------------------------------------------------------------------------
// 128x128 kernel (m97 structure, gload_lds) for the small/odd-shaped GEMMs.
// Swapped mfma operands + packed epilogue (R5-verified).
// ---------------------------------------------------------------------------
template <typename CT, bool BIAS, bool BROW>
__global__ __launch_bounds__(256) void gemm_nt(
    const __half* __restrict__ A, int lda, long long sA,
    const __half* __restrict__ Bt, int ldb, long long sB,
    const float* __restrict__ bias, long long sBias,
    CT* __restrict__ C, int ldc, long long sC,
    int nT, int K) {
  __shared__ __align__(16) __half As[128 * 64];
  __shared__ __align__(16) __half Bs[128 * 64];

  const int tid = threadIdx.x;
  const int wave = tid >> 6, lane = tid & 63;

  const int gsz = 8 * nT;
  const int g = blockIdx.x / gsz, r = blockIdx.x % gsz;
  const int m0 = (g * 8 + (r & 7)) * 128;
  const int n0 = (r >> 3) * 128;

  A += (long long)blockIdx.z * sA;
  Bt += (long long)blockIdx.z * sB;
  C += (long long)blockIdx.z * sC;
  if constexpr (BIAS || BROW) bias += (long long)blockIdx.z * sBias;
  const int wm = wave & 1, wn = wave >> 1;

  f32x4 acc[4][4];
#pragma unroll
  for (int i = 0; i < 4; ++i)
#pragma unroll
    for (int jj = 0; jj < 4; ++jj) acc[i][jj] = (f32x4){0.f, 0.f, 0.f, 0.f};

  const int srow = tid >> 3;
  const int gc = (tid & 7) ^ (srow & 7);
  const __half* Ag = A + (size_t)(m0 + srow) * lda + gc * 8;
  const __half* Bg = Bt + (size_t)(n0 + srow) * ldb + gc * 8;
  const size_t a32 = (size_t)32 * lda, b32 = (size_t)32 * ldb;
  char* AsW = (char*)As + wave * 1024;
  char* BsW = (char*)Bs + wave * 1024;

  const int ml = lane & 15, q = lane >> 4, lx = lane & 7;
  const int aoff = ((wm * 64 + ml) * 8 + (q ^ lx)) * 16;
  const int boff = ((wn * 64 + ml) * 8 + (q ^ lx)) * 16;

  for (int k0 = 0; k0 < K; k0 += 64) {
#pragma unroll
    for (int i = 0; i < 4; ++i) {
      async16(Ag + i * a32 + k0, AsW + i * 4096);
      async16(Bg + i * b32 + k0, BsW + i * 4096);
    }
    __syncthreads();
#pragma unroll
    for (int jj = 0; jj < 2; ++jj) {
      const char* Ab = (const char*)As + (jj ? (aoff ^ 64) : aoff);
      const char* Bb = (const char*)Bs + (jj ? (boff ^ 64) : boff);
      f16x8 af[4], bf[4];
#pragma unroll
      for (int i = 0; i < 4; ++i) {
        af[i] = *(const f16x8*)(Ab + i * 2048);
        bf[i] = *(const f16x8*)(Bb + i * 2048);
      }
#pragma unroll
      for (int i = 0; i < 4; ++i)
#pragma unroll
        for (int jn = 0; jn < 4; ++jn)
          acc[i][jn] = MFMA16(bf[jn], af[i], acc[i][jn]);
    }
    __syncthreads();
  }

  // swapped-layout packed epilogue
#pragma unroll
  for (int jn = 0; jn < 4; ++jn) {
    const int col0 = n0 + wn * 64 + jn * 16 + q * 4;
    float4 bc = {0.f, 0.f, 0.f, 0.f};
    if constexpr (BIAS) bc = *(const float4*)(bias + col0);
#pragma unroll
    for (int i = 0; i < 4; ++i) {
      const int row = m0 + wm * 64 + i * 16 + ml;
      const float br = BROW ? bias[row] : 0.f;
      const float v0 = acc[i][jn][0] + bc.x + br;
      const float v1 = acc[i][jn][1] + bc.y + br;
      const float v2 = acc[i][jn][2] + bc.z + br;
      const float v3 = acc[i][jn][3] + bc.w + br;
      if constexpr (sizeof(CT) == 4) {
        *(float4*)(C + (size_t)row * ldc + col0) = make_float4(v0, v1, v2, v3);
      } else {
        h4 o{__float2half(v0), __float2half(v1), __float2half(v2), __float2half(v3)};
        *(h4*)((__half*)C + (size_t)row * ldc + col0) = o;
      }
    }
  }
}

// ---------------------------------------------------------------------------
// prep: all 6 weight transposes (fp32 -> fp16) + bias concat. grid (2305, 6).
// ---------------------------------------------------------------------------
__global__ __launch_bounds__(256) void prep(
    const float* __restrict__ Wq, const float* __restrict__ Wk,
    const float* __restrict__ Wv, const float* __restrict__ W1,
    const float* __restrict__ Wo, const float* __restrict__ W2,
    const float* __restrict__ bq, const float* __restrict__ bk,
    __half* __restrict__ wD, __half* __restrict__ wB, __half* __restrict__ wC,
    __half* __restrict__ wA, float* __restrict__ bqk) {
  if (blockIdx.x == 2304) {
    if (blockIdx.y == 0)
      for (int i = threadIdx.x; i < 3072; i += 256) {
        bqk[i] = bq[i];
        bqk[3072 + i] = bk[i];
      }
    return;
  }
  __shared__ float t[32][33];
  const int tx = threadIdx.x & 31, ty = threadIdx.x >> 5;
  if (blockIdx.y < 4) {
    const float* in;
    __half* out;
    switch (blockIdx.y) {
      case 0: in = Wq; out = wD; break;
      case 1: in = Wk; out = wD + 3072 * 768; break;
      case 2: in = Wv; out = wB; break;
      default: in = W1; out = wC; break;
    }
    const int cb = blockIdx.x % 96, rb = blockIdx.x / 96;
    const int c = cb * 32 + tx, r0 = rb * 32;
#pragma unroll
    for (int i = 0; i < 32; i += 8) t[ty + i][tx] = in[(size_t)(r0 + ty + i) * 3072 + c];
    __syncthreads();
    const int oc = r0 + tx, o0 = cb * 32;
#pragma unroll
    for (int i = 0; i < 32; i += 8)
      out[(size_t)(o0 + ty + i) * 768 + oc] = __float2half(t[tx][ty + i]);
  } else {
    const float* in = (blockIdx.y == 5) ? W2 : Wo;
    __half* out = wA + ((blockIdx.y == 5) ? 3072 * 768 : 0);
    const int cb = blockIdx.x % 24, rb = blockIdx.x / 24;
    const int c = cb * 32 + tx, r0 = rb * 32;
#pragma unroll
    for (int i = 0; i < 32; i += 8) t[ty + i][tx] = in[(size_t)(r0 + ty + i) * 768 + c];
    __syncthreads();
    const int oc = r0 + tx, o0 = cb * 32;
#pragma unroll
    for (int i = 0; i < 32; i += 8)
      out[(size_t)(o0 + ty + i) * 3072 + oc] = __float2half(t[tx][ty + i]);
  }
}

// ---------------------------------------------------------------------------
__global__ __launch_bounds__(256) void embed_pos_kernel(
    const int* __restrict__ x, const float* __restrict__ emb,
    float* __restrict__ y, __half* __restrict__ yh) {
  const int row = blockIdx.x;  // b*1024 + s
  const int s = row & 1023;
  const int tok = x[row];
  const float* ep = emb + (size_t)tok * 768;
  float* yp = y + (size_t)row * 768;
  __half* hp = yh + (size_t)row * 768;
  const float c = -13.287712379549449f / 768.f;  // -log2(10000)/768
  for (int d = threadIdx.x; d < 768; d += 256) {
    float ang = (float)s * exp2f((float)d * c);
    float pe = (d & 1) ? cosf(ang) : sinf(ang);
    float v = ep[d] + pe;
    yp[d] = v;
    hp[d] = __float2half(v);
  }
}

// Row softmax over 1024 fp32 logits -> fp16 probs. One block per row.
__global__ __launch_bounds__(256) void softmax_rows(
    const float* __restrict__ L, __half* __restrict__ P) {
  const size_t row = blockIdx.x;
  const float4 x = ((const float4*)(L + row * 1024))[threadIdx.x];
  const int wave = threadIdx.x >> 6, lane = threadIdx.x & 63;
  float m = fmaxf(fmaxf(x.x, x.y), fmaxf(x.z, x.w));
  m = waveReduceMax(m);
  __shared__ float sm[4];
  __shared__ float ssum[4];
  if (lane == 0) sm[wave] = m;
  __syncthreads();
  m = fmaxf(fmaxf(sm[0], sm[1]), fmaxf(sm[2], sm[3]));
  float e0 = expf(x.x - m), e1 = expf(x.y - m), e2 = expf(x.z - m), e3 = expf(x.w - m);
  float s = e0 + e1 + e2 + e3;
  s = waveReduceSum(s);
  if (lane == 0) ssum[wave] = s;
  __syncthreads();
  s = ssum[0] + ssum[1] + ssum[2] + ssum[3];
  const float inv = 1.f / s;
  h4 o{__float2half(e0 * inv), __float2half(e1 * inv), __float2half(e2 * inv),
       __float2half(e3 * inv)};
  ((h4*)(P + row * 1024))[threadIdx.x] = o;
}

// y += [gelu](p0 + p1 + bias[d]) in-place + layernorm2d partial sums.
template <bool GELU>
__global__ __launch_bounds__(256) void residual_stats(
    float* __restrict__ y, const float* __restrict__ p0, const float* __restrict__ p1,
    const float* __restrict__ bias, float2* __restrict__ partials) {
  const int b = blockIdx.y, chunk = blockIdx.x;
  const size_t base = (size_t)b * 786432 + (size_t)chunk * 8192;
  float4* yp = (float4*)(y + base);
  const float4* a0 = (const float4*)(p0 + base);
  const float4* a1 = (const float4*)(p1 + base);
  float s = 0.f, ss = 0.f;
#pragma unroll
  for (int it = 0; it < 8; ++it) {
    const int idx = it * 256 + threadIdx.x;
    const int d = (chunk * 8192 + it * 1024 + threadIdx.x * 4) % 768;
    float4 yv = yp[idx];
    float4 v0 = a0[idx];
    float4 v1 = a1[idx];
    const float4 bv = *(const float4*)(bias + d);
    float ax = v0.x + v1.x + bv.x, ay = v0.y + v1.y + bv.y;
    float az = v0.z + v1.z + bv.z, aw = v0.w + v1.w + bv.w;
    if constexpr (GELU) {
      ax = gelu_exact(ax); ay = gelu_exact(ay);
      az = gelu_exact(az); aw = gelu_exact(aw);
    }
    float4 r{yv.x + ax, yv.y + ay, yv.z + az, yv.w + aw};
    yp[idx] = r;
    s += r.x + r.y + r.z + r.w;
    ss += r.x * r.x + r.y * r.y + r.z * r.z + r.w * r.w;
  }
  s = waveReduceSum(s);
  ss = waveReduceSum(ss);
  __shared__ float2 wr[4];
  const int wave = threadIdx.x >> 6, lane = threadIdx.x & 63;
  if (lane == 0) wr[wave] = make_float2(s, ss);
  __syncthreads();
  if (threadIdx.x == 0) {
    float S = wr[0].x + wr[1].x + wr[2].x + wr[3].x;
    float SS = wr[0].y + wr[1].y + wr[2].y + wr[3].y;
    partials[b * 96 + chunk] = make_float2(S, SS);
  }
}

// Finalize (reduce 96 partials in-block) + apply LN; grid 6144.
template <bool WB>
__global__ __launch_bounds__(256) void ln_apply(
    float* __restrict__ y, __half* __restrict__ yh, const float* __restrict__ w,
    const float* __restrict__ bb, const float2* __restrict__ partials) {
  const unsigned i4 = blockIdx.x * 256 + threadIdx.x;
  const unsigned i = i4 * 4;
  const unsigned b = i / 786432u;
  const int tid = threadIdx.x;
  float s = 0.f, ss = 0.f;
  if (tid < 96) {
    float2 p = partials[b * 96 + tid];
    s = p.x;
    ss = p.y;
  }
  s = waveReduceSum(s);
  ss = waveReduceSum(ss);
  __shared__ float2 wsum[4];
  if ((tid & 63) == 0) wsum[tid >> 6] = make_float2(s, ss);
  __syncthreads();
  const float S = wsum[0].x + wsum[1].x + wsum[2].x + wsum[3].x;
  const float SS = wsum[0].y + wsum[1].y + wsum[2].y + wsum[3].y;
  const float inv = 1.f / 786432.f;
  const float mean = S * inv;
  const float rstd = rsqrtf(SS * inv - mean * mean + 1e-5f);

  const unsigned e4 = (i - b * 786432u) >> 2;
  float4 yv = ((const float4*)y)[i4];
  const float4 wv = ((const float4*)w)[e4];
  const float4 bv = ((const float4*)bb)[e4];
  float4 r;
  r.x = (yv.x - mean) * rstd * wv.x + bv.x;
  r.y = (yv.y - mean) * rstd * wv.y + bv.y;
  r.z = (yv.z - mean) * rstd * wv.z + bv.z;
  r.w = (yv.w - mean) * rstd * wv.w + bv.w;
  ((float4*)y)[i4] = r;
  if constexpr (WB) {
    h4 o{__float2half(r.x), __float2half(r.y), __float2half(r.z), __float2half(r.w)};
    ((h4*)yh)[i4] = o;
  }
}

// ---------------------------------------------------------------------------
extern "C" void kernel_launch(void* const* d_in, const int* in_sizes, int n_in,
                              void* d_out, int out_size, void* d_ws, size_t ws_size,
                              hipStream_t stream) {
  const int* x = (const int*)d_in[0];
  const float* emb = (const float*)d_in[1];
  const float* Wq = (const float*)d_in[2];
  const float* bq = (const float*)d_in[3];
  const float* Wk = (const float*)d_in[4];
  const float* bk = (const float*)d_in[5];
  const float* Wv = (const float*)d_in[6];
  const float* bv = (const float*)d_in[7];
  const float* Wo = (const float*)d_in[8];
  const float* bo = (const float*)d_in[9];
  const float* W1 = (const float*)d_in[10];
  const float* b1 = (const float*)d_in[11];
  const float* W2 = (const float*)d_in[12];
  const float* b2 = (const float*)d_in[13];
  const float* ln1w = (const float*)d_in[14];
  const float* ln1b = (const float*)d_in[15];
  const float* ln2w = (const float*)d_in[16];
  const float* ln2b = (const float*)d_in[17];

  float* y = (float*)d_out;  // [8,1024,768] fp32 residual stream

  // ---- workspace map (liveness overlays), total 225.5 MB ----
  char* ws = (char*)d_ws;
  __half* yh = (__half*)(ws + 0);            // 12.58 MB fp16 residual stream
  __half* qb = (__half*)(ws + 12582912);     // 50.33 MB q -> av -> f1
  __half* kb = (__half*)(ws + 62914560);     // 50.33 MB k -> Ph
  __half* Ph = kb;
  __half* vT = (__half*)(ws + 113246208);    // 50.33 MB v^T -> abuf (2x25.17 split-K)
  float* abuf = (float*)vT;
  float* Lg = (float*)(ws + 163577856);      // 33.55 MB logits fp32
  __half* wA = (__half*)(ws + 197132288);    // 9.44 MB Wo^T|W2^T
  __half* wD = (__half*)(ws + 206569472);    // 9.44 MB Wq^T|Wk^T
  __half* wB = (__half*)(ws + 216006656);    // 4.72 MB Wv^T
  __half* wC = (__half*)(ws + 220725248);    // 4.72 MB W1^T
  float* bqk = (float*)(ws + 225443840);     // 24 KB bq|bk
  float2* part = (float2*)(ws + 225468416);  // 6 KB
  const size_t WS_NEEDED = 225474624;
  if (ws_size < WS_NEEDED) return;

  const dim3 blk(256), blk8(512);
  const long long SH = 1024LL * 3072, SS = 1024LL * 1024;
  const long long HALF = 25165824;  // q->k element stride (8192*3072)
  float* p1 = abuf + 6291456;       // second split-K partial

  prep<<<dim3(2305, 6), blk, 0, stream>>>(Wq, Wk, Wv, W1, Wo, W2, bq, bk, wD, wB, wC, wA, bqk);
  embed_pos_kernel<<<dim3(8192), blk, 0, stream>>>(x, emb, y, yh);

  // q,k = yh @ {Wq,Wk} + {bq,bk}: M=8192 N=3072 K=768 (768 blocks = 3 rounds)
  gemm_nt8<__half, true, false><<<dim3(384, 1, 2), blk8, 0, stream>>>(
      yh, 768, 0, wD, 768, 3072LL * 768, bqk, 3072, qb, 3072, HALF, 12, 768);

  // vT[b][n][s] = sum_k Wv[k][n]*y[b][s][k] + bv[n]  (128^2: 1536 blocks)
  gemm_nt<__half, false, true><<<dim3(192, 1, 8), blk, 0, stream>>>(
      wB, 768, 0, yh, 768, 1024LL * 768, bv, 0, vT, 1024, SH, 8, 768);

  // logits = q k^T (fp32), per batch (128^2)
  gemm_nt<float, false, false><<<dim3(64, 1, 8), blk, 0, stream>>>(
      qb, 3072, SH, kb, 3072, SH, nullptr, 0, Lg, 1024, SS, 8, 3072);

  softmax_rows<<<dim3(8192), blk, 0, stream>>>(Lg, Ph);  // Ph overlays k (dead)

  // av = P @ V (Bt = v^T), per batch (128^2: 1536 blocks); av overlays q
  gemm_nt<__half, false, false><<<dim3(192, 1, 8), blk, 0, stream>>>(
      Ph, 1024, SS, vT, 1024, SH, nullptr, 0, (__half*)qb, 3072, SH, 24, 1024);

  // a = av @ Wo (split-K=2, 128^2: 768 blocks) -> abuf over vT
  gemm_nt<float, false, false><<<dim3(384, 1, 2), blk, 0, stream>>>(
      (__half*)qb, 3072, 1536, wA, 3072, 1536, nullptr, 0, abuf, 768, 6291456, 6, 1536);

  // y = ln1(y + a + bo)
  residual_stats<false><<<dim3(96, 8), blk, 0, stream>>>(y, abuf, p1, bo, part);
  ln_apply<true><<<dim3(6144), blk, 0, stream>>>(y, yh, ln1w, ln1b, part);

  // f1 = y@W1 + b1: M=8192 N=3072 K=768 (384 blocks = 1.5 rounds, 8-phase)
  gemm_nt8<__half, true, false><<<dim3(384, 1, 1), blk8, 0, stream>>>(
      yh, 768, 0, wC, 768, 0, b1, 0, (__half*)qb, 3072, 0, 12, 768);
  // f = f1@W2 (split-K=2, 128^2: 768 blocks; bias b2 + gelu in residual) -> abuf
  gemm_nt<float, false, false><<<dim3(384, 1, 2), blk, 0, stream>>>(
      (__half*)qb, 3072, 1536, wA + 3072 * 768, 3072, 1536, nullptr, 0, abuf, 768, 6291456, 6, 1536);

  // y = ln2(y + gelu(f + b2))
  residual_stats<true><<<dim3(96, 8), blk, 0, stream>>>(y, abuf, p1, b2, part);
  ln_apply<false><<<dim3(6144), blk, 0, stream>>>(y, nullptr, ln2w, ln2b, part);
}

// Round 7
// 738.546 us; speedup vs baseline: 1.0106x; 1.0106x over previous
//
#include <hip/hip_runtime.h>
#include <hip/hip_fp16.h>

#define DI __device__ __forceinline__

typedef _Float16 f16x8 __attribute__((ext_vector_type(8)));
typedef float f32x4 __attribute__((ext_vector_type(4)));

struct alignas(8) h4 { __half x, y, z, w; };

DI float waveReduceSum(float v) {
#pragma unroll
  for (int i = 1; i < 64; i <<= 1) v += __shfl_xor(v, i);
  return v;
}
DI float waveReduceMax(float v) {
#pragma unroll
  for (int i = 1; i < 64; i <<= 1) v = fmaxf(v, __shfl_xor(v, i));
  return v;
}

DI float gelu_exact(float x) { return 0.5f * x * (1.f + erff(x * 0.70710678118654752f)); }

#define MFMA16(b_, a_, c_) __builtin_amdgcn_mfma_f32_16x16x32_f16((b_), (a_), (c_), 0, 0, 0)

// ---------------------------------------------------------------------------
// gemm_nt8 — R5-verified best (716 TF on qk): 256x256 tile, BK=64, 512 thr
// (8 waves = 2M x 4N, wave-tile 128x64, acc[8][4]). REG-STAGED pipeline:
//   iter t: DSW(t+1) (regs->slot (t+1)&1; LDG flew under prev MFMAs);
//           LDG(t+2) issue; 64 MFMA on slot t&1; lgkm0 + barrier.
// One barrier per K-tile; prefetch never drained by vmcnt(0).
// R6 lesson: 8-phase gload_lds variant = 122.8us (old plateau); this = 108.7.
// Swapped-operand MFMA + packed float4/h4 epilogue; XOR-chunk LDS layout.
// ---------------------------------------------------------------------------
template <typename CT, bool BIAS, bool BROW>
__global__ __launch_bounds__(512, 2) void gemm_nt8(
    const __half* __restrict__ A, int lda, long long sA,
    const __half* __restrict__ Bt, int ldb, long long sB,
    const float* __restrict__ bias, long long sBias,
    CT* __restrict__ C, int ldc, long long sC,
    int nT, int K) {
  __shared__ __align__(16) __half As[2][16384];  // 2 slots x 256x64
  __shared__ __align__(16) __half Bs[2][16384];

  const int tid = threadIdx.x;
  const int wave = tid >> 6, lane = tid & 63;

  // GROUP_M=4 swizzled block decode (all mT here divisible by 4)
  const int gsz = 4 * nT;
  const int g = blockIdx.x / gsz, r = blockIdx.x % gsz;
  const int m0 = (g * 4 + (r & 3)) * 256;
  const int n0 = (r >> 2) * 256;

  A += (long long)blockIdx.z * sA;
  Bt += (long long)blockIdx.z * sB;
  C += (long long)blockIdx.z * sC;
  if constexpr (BIAS || BROW) bias += (long long)blockIdx.z * sBias;

  const int wm = wave >> 2, wn = wave & 3;

  f32x4 acc[8][4];
#pragma unroll
  for (int i = 0; i < 8; ++i)
#pragma unroll
    for (int j = 0; j < 4; ++j) acc[i][j] = (f32x4){0.f, 0.f, 0.f, 0.f};

  // staging: load-chunk j of thread t maps to rows j*64 + (t>>3); slot col
  // (t&7) holds global chunk (t&7)^((t>>3)&7). 512 thr x 16B = 64 rows/chunk.
  const int srow = tid >> 3;
  const int gc = (tid & 7) ^ (srow & 7);
  const __half* Ag = A + (size_t)(m0 + srow) * lda + gc * 8;
  const __half* Bg = Bt + (size_t)(n0 + srow) * ldb + gc * 8;
  const size_t a64 = (size_t)64 * lda, b64 = (size_t)64 * ldb;
  char* AsWr = (char*)As + tid * 16;  // linear layout (same as gload_lds wrote)
  char* BsWr = (char*)Bs + tid * 16;

  f16x8 sra[4], srb[4];  // in-flight staging registers (one K-tile)

#define LDG(t)                                                        \
  {                                                                   \
    const __half* sa_ = Ag + (t) * 64;                                \
    const __half* sb_ = Bg + (t) * 64;                                \
    sra[0] = *(const f16x8*)(sa_);                                    \
    sra[1] = *(const f16x8*)(sa_ + a64);                              \
    sra[2] = *(const f16x8*)(sa_ + 2 * a64);                          \
    sra[3] = *(const f16x8*)(sa_ + 3 * a64);                          \
    srb[0] = *(const f16x8*)(sb_);                                    \
    srb[1] = *(const f16x8*)(sb_ + b64);                              \
    srb[2] = *(const f16x8*)(sb_ + 2 * b64);                          \
    srb[3] = *(const f16x8*)(sb_ + 3 * b64);                          \
  }
#define DSW(t)                                                        \
  {                                                                   \
    char* da_ = AsWr + (((t) & 1) ? 32768 : 0);                       \
    char* db_ = BsWr + (((t) & 1) ? 32768 : 0);                       \
    *(f16x8*)(da_) = sra[0];                                          \
    *(f16x8*)(da_ + 8192) = sra[1];                                   \
    *(f16x8*)(da_ + 16384) = sra[2];                                  \
    *(f16x8*)(da_ + 24576) = sra[3];                                  \
    *(f16x8*)(db_) = srb[0];                                          \
    *(f16x8*)(db_ + 8192) = srb[1];                                   \
    *(f16x8*)(db_ + 16384) = srb[2];                                  \
    *(f16x8*)(db_ + 24576) = srb[3];                                  \
  }

  // frag read bases: A row = wm*128 + mi*16 + ml; B row = wn*64 + nj*16 + ml.
  // chunk byte co0 (kstep0) / co0^64 (kstep1); row&7 == ml&7 so XOR layout holds.
  const int ml = lane & 15, q = lane >> 4, lx = lane & 7;
  const int co0 = (q ^ lx) * 16, co1 = co0 ^ 64;
  const char* Ar = (const char*)As + wm * 16384 + ml * 128;
  const char* Br = (const char*)Bs + (wn >> 1) * 16384 + (wn & 1) * 8192 + ml * 128;

  const int nt = K >> 6;
  // prologue: tile0 -> slot0 (compiler inserts the vmcnt wait for sra/srb use)
  LDG(0);
  DSW(0);
  if (nt > 1) LDG(1);
  asm volatile("s_waitcnt lgkmcnt(0)" ::: "memory");
  __builtin_amdgcn_s_barrier();
  __builtin_amdgcn_sched_barrier(0);

  for (int t = 0; t < nt; ++t) {
    // stage tile t+1 (regs -> slot (t+1)&1) early; its LDG flew during the
    // previous iteration's MFMAs. Then issue LDG(t+2).
    if (t + 1 < nt) {
      DSW(t + 1);
      if (t + 2 < nt) LDG(t + 2);
    }
    // compute tile t from slot t&1
    const int pb = (t & 1) ? 32768 : 0;
    const char* Ap = Ar + pb;
    const char* Bp = Br + pb;
    f16x8 af[8], bf[4];
#pragma unroll
    for (int ks = 0; ks < 2; ++ks) {
      const int co = ks ? co1 : co0;
#pragma unroll
      for (int i = 0; i < 8; ++i) af[i] = *(const f16x8*)(Ap + i * 2048 + co);
#pragma unroll
      for (int j = 0; j < 4; ++j) bf[j] = *(const f16x8*)(Bp + j * 2048 + co);
#pragma unroll
      for (int i = 0; i < 8; ++i)
#pragma unroll
        for (int j = 0; j < 4; ++j)
          acc[i][j] = MFMA16(bf[j], af[i], acc[i][j]);
    }
    // fence: my ds_writes + ds_reads complete, then barrier (rule #18).
    asm volatile("s_waitcnt lgkmcnt(0)" ::: "memory");
    __builtin_amdgcn_s_barrier();
    __builtin_amdgcn_sched_barrier(0);
  }
#undef LDG
#undef DSW

  // epilogue (swapped layout): frag (i,j) holds C[m0+wm*128+i*16+ml]
  // [n0+wn*64+j*16+q*4 + rr], rr=0..3 -> packed 8B/16B stores.
#pragma unroll
  for (int j = 0; j < 4; ++j) {
    const int col0 = n0 + wn * 64 + j * 16 + q * 4;
    float4 bc = {0.f, 0.f, 0.f, 0.f};
    if constexpr (BIAS) bc = *(const float4*)(bias + col0);
#pragma unroll
    for (int i = 0; i < 8; ++i) {
      const int row = m0 + wm * 128 + i * 16 + ml;
      const float br = BROW ? bias[row] : 0.f;
      const float v0 = acc[i][j][0] + bc.x + br;
      const float v1 = acc[i][j][1] + bc.y + br;
      const float v2 = acc[i][j][2] + bc.z + br;
      const float v3 = acc[i][j][3] + bc.w + br;
      if constexpr (sizeof(CT) == 4) {
        *(float4*)(C + (size_t)row * ldc + col0) = make_float4(v0, v1, v2, v3);
      } else {
        h4 o{__float2half(v0), __float2half(v1), __float2half(v2), __float2half(v3)};
        *(h4*)((__half*)C + (size_t)row * ldc + col0) = o;
      }
    }
  }
}

// ---------------------------------------------------------------------------
// gemm_nt — 128x128 tile, NOW with the R5 reg-staged pipeline ported down:
// double-buffered LDS (2 x 32KB = 64KB -> 2 blocks/CU, TLP preserved),
// LDG->VGPR->ds_write staging, ONE lgkm-fenced barrier per K-tile (was
// vmcnt(0)-drain + 2 syncthreads). Staging addresses identical to what
// global_load_lds produced (linear, XOR-chunk), so the verified read path is
// unchanged except the slot offset. Packed swapped-operand epilogue kept.
// ---------------------------------------------------------------------------
template <typename CT, bool BIAS, bool BROW>
__global__ __launch_bounds__(256, 2) void gemm_nt(
    const __half* __restrict__ A, int lda, long long sA,
    const __half* __restrict__ Bt, int ldb, long long sB,
    const float* __restrict__ bias, long long sBias,
    CT* __restrict__ C, int ldc, long long sC,
    int nT, int K) {
  __shared__ __align__(16) __half As[2][8192];  // 2 slots x 128x64
  __shared__ __align__(16) __half Bs[2][8192];

  const int tid = threadIdx.x;
  const int wave = tid >> 6, lane = tid & 63;

  const int gsz = 8 * nT;
  const int g = blockIdx.x / gsz, r = blockIdx.x % gsz;
  const int m0 = (g * 8 + (r & 7)) * 128;
  const int n0 = (r >> 3) * 128;

  A += (long long)blockIdx.z * sA;
  Bt += (long long)blockIdx.z * sB;
  C += (long long)blockIdx.z * sC;
  if constexpr (BIAS || BROW) bias += (long long)blockIdx.z * sBias;
  const int wm = wave & 1, wn = wave >> 1;

  f32x4 acc[4][4];
#pragma unroll
  for (int i = 0; i < 4; ++i)
#pragma unroll
    for (int jj = 0; jj < 4; ++jj) acc[i][jj] = (f32x4){0.f, 0.f, 0.f, 0.f};

  // staging: chunk i of thread t covers rows i*32 + (t>>3); slot col (t&7)
  // holds global chunk (t&7)^(row&7). 256 thr x 16B = 32 rows / chunk.
  const int srow = tid >> 3;
  const int gc = (tid & 7) ^ (srow & 7);
  const __half* Ag = A + (size_t)(m0 + srow) * lda + gc * 8;
  const __half* Bg = Bt + (size_t)(n0 + srow) * ldb + gc * 8;
  const size_t a32 = (size_t)32 * lda, b32 = (size_t)32 * ldb;
  char* AsWr = (char*)As + tid * 16;
  char* BsWr = (char*)Bs + tid * 16;

  f16x8 sra[4], srb[4];

#define LDG(t)                                                        \
  {                                                                   \
    const __half* sa_ = Ag + (t) * 64;                                \
    const __half* sb_ = Bg + (t) * 64;                                \
    sra[0] = *(const f16x8*)(sa_);                                    \
    sra[1] = *(const f16x8*)(sa_ + a32);                              \
    sra[2] = *(const f16x8*)(sa_ + 2 * a32);                          \
    sra[3] = *(const f16x8*)(sa_ + 3 * a32);                          \
    srb[0] = *(const f16x8*)(sb_);                                    \
    srb[1] = *(const f16x8*)(sb_ + b32);                              \
    srb[2] = *(const f16x8*)(sb_ + 2 * b32);                          \
    srb[3] = *(const f16x8*)(sb_ + 3 * b32);                          \
  }
#define DSW(t)                                                        \
  {                                                                   \
    char* da_ = AsWr + (((t) & 1) ? 16384 : 0);                       \
    char* db_ = BsWr + (((t) & 1) ? 16384 : 0);                       \
    *(f16x8*)(da_) = sra[0];                                          \
    *(f16x8*)(da_ + 4096) = sra[1];                                   \
    *(f16x8*)(da_ + 8192) = sra[2];                                   \
    *(f16x8*)(da_ + 12288) = sra[3];                                  \
    *(f16x8*)(db_) = srb[0];                                          \
    *(f16x8*)(db_ + 4096) = srb[1];                                   \
    *(f16x8*)(db_ + 8192) = srb[2];                                   \
    *(f16x8*)(db_ + 12288) = srb[3];                                  \
  }

  const int ml = lane & 15, q = lane >> 4, lx = lane & 7;
  const int aoff = ((wm * 64 + ml) * 8 + (q ^ lx)) * 16;
  const int boff = ((wn * 64 + ml) * 8 + (q ^ lx)) * 16;

  const int nt = K >> 6;
  LDG(0);
  DSW(0);
  if (nt > 1) LDG(1);
  asm volatile("s_waitcnt lgkmcnt(0)" ::: "memory");
  __builtin_amdgcn_s_barrier();
  __builtin_amdgcn_sched_barrier(0);

  for (int t = 0; t < nt; ++t) {
    if (t + 1 < nt) {
      DSW(t + 1);
      if (t + 2 < nt) LDG(t + 2);
    }
    const int pb = (t & 1) ? 16384 : 0;
#pragma unroll
    for (int jj = 0; jj < 2; ++jj) {
      const char* Ab = (const char*)As + pb + (jj ? (aoff ^ 64) : aoff);
      const char* Bb = (const char*)Bs + pb + (jj ? (boff ^ 64) : boff);
      f16x8 af[4], bf[4];
#pragma unroll
      for (int i = 0; i < 4; ++i) {
        af[i] = *(const f16x8*)(Ab + i * 2048);
        bf[i] = *(const f16x8*)(Bb + i * 2048);
      }
#pragma unroll
      for (int i = 0; i < 4; ++i)
#pragma unroll
        for (int jn = 0; jn < 4; ++jn)
          acc[i][jn] = MFMA16(bf[jn], af[i], acc[i][jn]);
    }
    asm volatile("s_waitcnt lgkmcnt(0)" ::: "memory");
    __builtin_amdgcn_s_barrier();
    __builtin_amdgcn_sched_barrier(0);
  }
#undef LDG
#undef DSW

  // swapped-layout packed epilogue
#pragma unroll
  for (int jn = 0; jn < 4; ++jn) {
    const int col0 = n0 + wn * 64 + jn * 16 + q * 4;
    float4 bc = {0.f, 0.f, 0.f, 0.f};
    if constexpr (BIAS) bc = *(const float4*)(bias + col0);
#pragma unroll
    for (int i = 0; i < 4; ++i) {
      const int row = m0 + wm * 64 + i * 16 + ml;
      const float br = BROW ? bias[row] : 0.f;
      const float v0 = acc[i][jn][0] + bc.x + br;
      const float v1 = acc[i][jn][1] + bc.y + br;
      const float v2 = acc[i][jn][2] + bc.z + br;
      const float v3 = acc[i][jn][3] + bc.w + br;
      if constexpr (sizeof(CT) == 4) {
        *(float4*)(C + (size_t)row * ldc + col0) = make_float4(v0, v1, v2, v3);
      } else {
        h4 o{__float2half(v0), __float2half(v1), __float2half(v2), __float2half(v3)};
        *(h4*)((__half*)C + (size_t)row * ldc + col0) = o;
      }
    }
  }
}

// ---------------------------------------------------------------------------
// prep: all 6 weight transposes (fp32 -> fp16) + bias concat. grid (2305, 6).
// ---------------------------------------------------------------------------
__global__ __launch_bounds__(256) void prep(
    const float* __restrict__ Wq, const float* __restrict__ Wk,
    const float* __restrict__ Wv, const float* __restrict__ W1,
    const float* __restrict__ Wo, const float* __restrict__ W2,
    const float* __restrict__ bq, const float* __restrict__ bk,
    __half* __restrict__ wD, __half* __restrict__ wB, __half* __restrict__ wC,
    __half* __restrict__ wA, float* __restrict__ bqk) {
  if (blockIdx.x == 2304) {
    if (blockIdx.y == 0)
      for (int i = threadIdx.x; i < 3072; i += 256) {
        bqk[i] = bq[i];
        bqk[3072 + i] = bk[i];
      }
    return;
  }
  __shared__ float t[32][33];
  const int tx = threadIdx.x & 31, ty = threadIdx.x >> 5;
  if (blockIdx.y < 4) {
    const float* in;
    __half* out;
    switch (blockIdx.y) {
      case 0: in = Wq; out = wD; break;
      case 1: in = Wk; out = wD + 3072 * 768; break;
      case 2: in = Wv; out = wB; break;
      default: in = W1; out = wC; break;
    }
    const int cb = blockIdx.x % 96, rb = blockIdx.x / 96;
    const int c = cb * 32 + tx, r0 = rb * 32;
#pragma unroll
    for (int i = 0; i < 32; i += 8) t[ty + i][tx] = in[(size_t)(r0 + ty + i) * 3072 + c];
    __syncthreads();
    const int oc = r0 + tx, o0 = cb * 32;
#pragma unroll
    for (int i = 0; i < 32; i += 8)
      out[(size_t)(o0 + ty + i) * 768 + oc] = __float2half(t[tx][ty + i]);
  } else {
    const float* in = (blockIdx.y == 5) ? W2 : Wo;
    __half* out = wA + ((blockIdx.y == 5) ? 3072 * 768 : 0);
    const int cb = blockIdx.x % 24, rb = blockIdx.x / 24;
    const int c = cb * 32 + tx, r0 = rb * 32;
#pragma unroll
    for (int i = 0; i < 32; i += 8) t[ty + i][tx] = in[(size_t)(r0 + ty + i) * 768 + c];
    __syncthreads();
    const int oc = r0 + tx, o0 = cb * 32;
#pragma unroll
    for (int i = 0; i < 32; i += 8)
      out[(size_t)(o0 + ty + i) * 3072 + oc] = __float2half(t[tx][ty + i]);
  }
}

// ---------------------------------------------------------------------------
__global__ __launch_bounds__(256) void embed_pos_kernel(
    const int* __restrict__ x, const float* __restrict__ emb,
    float* __restrict__ y, __half* __restrict__ yh) {
  const int row = blockIdx.x;  // b*1024 + s
  const int s = row & 1023;
  const int tok = x[row];
  const float* ep = emb + (size_t)tok * 768;
  float* yp = y + (size_t)row * 768;
  __half* hp = yh + (size_t)row * 768;
  const float c = -13.287712379549449f / 768.f;  // -log2(10000)/768
  for (int d = threadIdx.x; d < 768; d += 256) {
    float ang = (float)s * exp2f((float)d * c);
    float pe = (d & 1) ? cosf(ang) : sinf(ang);
    float v = ep[d] + pe;
    yp[d] = v;
    hp[d] = __float2half(v);
  }
}

// Row softmax over 1024 fp32 logits -> fp16 probs. One block per row.
__global__ __launch_bounds__(256) void softmax_rows(
    const float* __restrict__ L, __half* __restrict__ P) {
  const size_t row = blockIdx.x;
  const float4 x = ((const float4*)(L + row * 1024))[threadIdx.x];
  const int wave = threadIdx.x >> 6, lane = threadIdx.x & 63;
  float m = fmaxf(fmaxf(x.x, x.y), fmaxf(x.z, x.w));
  m = waveReduceMax(m);
  __shared__ float sm[4];
  __shared__ float ssum[4];
  if (lane == 0) sm[wave] = m;
  __syncthreads();
  m = fmaxf(fmaxf(sm[0], sm[1]), fmaxf(sm[2], sm[3]));
  float e0 = expf(x.x - m), e1 = expf(x.y - m), e2 = expf(x.z - m), e3 = expf(x.w - m);
  float s = e0 + e1 + e2 + e3;
  s = waveReduceSum(s);
  if (lane == 0) ssum[wave] = s;
  __syncthreads();
  s = ssum[0] + ssum[1] + ssum[2] + ssum[3];
  const float inv = 1.f / s;
  h4 o{__float2half(e0 * inv), __float2half(e1 * inv), __float2half(e2 * inv),
       __float2half(e3 * inv)};
  ((h4*)(P + row * 1024))[threadIdx.x] = o;
}

// y += [gelu](p0 + p1 + bias[d]) in-place + layernorm2d partial sums.
template <bool GELU>
__global__ __launch_bounds__(256) void residual_stats(
    float* __restrict__ y, const float* __restrict__ p0, const float* __restrict__ p1,
    const float* __restrict__ bias, float2* __restrict__ partials) {
  const int b = blockIdx.y, chunk = blockIdx.x;
  const size_t base = (size_t)b * 786432 + (size_t)chunk * 8192;
  float4* yp = (float4*)(y + base);
  const float4* a0 = (const float4*)(p0 + base);
  const float4* a1 = (const float4*)(p1 + base);
  float s = 0.f, ss = 0.f;
#pragma unroll
  for (int it = 0; it < 8; ++it) {
    const int idx = it * 256 + threadIdx.x;
    const int d = (chunk * 8192 + it * 1024 + threadIdx.x * 4) % 768;
    float4 yv = yp[idx];
    float4 v0 = a0[idx];
    float4 v1 = a1[idx];
    const float4 bv = *(const float4*)(bias + d);
    float ax = v0.x + v1.x + bv.x, ay = v0.y + v1.y + bv.y;
    float az = v0.z + v1.z + bv.z, aw = v0.w + v1.w + bv.w;
    if constexpr (GELU) {
      ax = gelu_exact(ax); ay = gelu_exact(ay);
      az = gelu_exact(az); aw = gelu_exact(aw);
    }
    float4 r{yv.x + ax, yv.y + ay, yv.z + az, yv.w + aw};
    yp[idx] = r;
    s += r.x + r.y + r.z + r.w;
    ss += r.x * r.x + r.y * r.y + r.z * r.z + r.w * r.w;
  }
  s = waveReduceSum(s);
  ss = waveReduceSum(ss);
  __shared__ float2 wr[4];
  const int wave = threadIdx.x >> 6, lane = threadIdx.x & 63;
  if (lane == 0) wr[wave] = make_float2(s, ss);
  __syncthreads();
  if (threadIdx.x == 0) {
    float S = wr[0].x + wr[1].x + wr[2].x + wr[3].x;
    float SS = wr[0].y + wr[1].y + wr[2].y + wr[3].y;
    partials[b * 96 + chunk] = make_float2(S, SS);
  }
}

// Finalize (reduce 96 partials in-block) + apply LN; grid 6144.
template <bool WB>
__global__ __launch_bounds__(256) void ln_apply(
    float* __restrict__ y, __half* __restrict__ yh, const float* __restrict__ w,
    const float* __restrict__ bb, const float2* __restrict__ partials) {
  const unsigned i4 = blockIdx.x * 256 + threadIdx.x;
  const unsigned i = i4 * 4;
  const unsigned b = i / 786432u;
  const int tid = threadIdx.x;
  float s = 0.f, ss = 0.f;
  if (tid < 96) {
    float2 p = partials[b * 96 + tid];
    s = p.x;
    ss = p.y;
  }
  s = waveReduceSum(s);
  ss = waveReduceSum(ss);
  __shared__ float2 wsum[4];
  if ((tid & 63) == 0) wsum[tid >> 6] = make_float2(s, ss);
  __syncthreads();
  const float S = wsum[0].x + wsum[1].x + wsum[2].x + wsum[3].x;
  const float SS = wsum[0].y + wsum[1].y + wsum[2].y + wsum[3].y;
  const float inv = 1.f / 786432.f;
  const float mean = S * inv;
  const float rstd = rsqrtf(SS * inv - mean * mean + 1e-5f);

  const unsigned e4 = (i - b * 786432u) >> 2;
  float4 yv = ((const float4*)y)[i4];
  const float4 wv = ((const float4*)w)[e4];
  const float4 bv = ((const float4*)bb)[e4];
  float4 r;
  r.x = (yv.x - mean) * rstd * wv.x + bv.x;
  r.y = (yv.y - mean) * rstd * wv.y + bv.y;
  r.z = (yv.z - mean) * rstd * wv.z + bv.z;
  r.w = (yv.w - mean) * rstd * wv.w + bv.w;
  ((float4*)y)[i4] = r;
  if constexpr (WB) {
    h4 o{__float2half(r.x), __float2half(r.y), __float2half(r.z), __float2half(r.w)};
    ((h4*)yh)[i4] = o;
  }
}

// ---------------------------------------------------------------------------
extern "C" void kernel_launch(void* const* d_in, const int* in_sizes, int n_in,
                              void* d_out, int out_size, void* d_ws, size_t ws_size,
                              hipStream_t stream) {
  const int* x = (const int*)d_in[0];
  const float* emb = (const float*)d_in[1];
  const float* Wq = (const float*)d_in[2];
  const float* bq = (const float*)d_in[3];
  const float* Wk = (const float*)d_in[4];
  const float* bk = (const float*)d_in[5];
  const float* Wv = (const float*)d_in[6];
  const float* bv = (const float*)d_in[7];
  const float* Wo = (const float*)d_in[8];
  const float* bo = (const float*)d_in[9];
  const float* W1 = (const float*)d_in[10];
  const float* b1 = (const float*)d_in[11];
  const float* W2 = (const float*)d_in[12];
  const float* b2 = (const float*)d_in[13];
  const float* ln1w = (const float*)d_in[14];
  const float* ln1b = (const float*)d_in[15];
  const float* ln2w = (const float*)d_in[16];
  const float* ln2b = (const float*)d_in[17];

  float* y = (float*)d_out;  // [8,1024,768] fp32 residual stream

  // ---- workspace map (liveness overlays), total 225.5 MB ----
  char* ws = (char*)d_ws;
  __half* yh = (__half*)(ws + 0);            // 12.58 MB fp16 residual stream
  __half* qb = (__half*)(ws + 12582912);     // 50.33 MB q -> av -> f1
  __half* kb = (__half*)(ws + 62914560);     // 50.33 MB k -> Ph
  __half* Ph = kb;
  __half* vT = (__half*)(ws + 113246208);    // 50.33 MB v^T -> abuf (2x25.17 split-K)
  float* abuf = (float*)vT;
  float* Lg = (float*)(ws + 163577856);      // 33.55 MB logits fp32
  __half* wA = (__half*)(ws + 197132288);    // 9.44 MB Wo^T|W2^T
  __half* wD = (__half*)(ws + 206569472);    // 9.44 MB Wq^T|Wk^T
  __half* wB = (__half*)(ws + 216006656);    // 4.72 MB Wv^T
  __half* wC = (__half*)(ws + 220725248);    // 4.72 MB W1^T
  float* bqk = (float*)(ws + 225443840);     // 24 KB bq|bk
  float2* part = (float2*)(ws + 225468416);  // 6 KB
  const size_t WS_NEEDED = 225474624;
  if (ws_size < WS_NEEDED) return;

  const dim3 blk(256), blk8(512);
  const long long SH = 1024LL * 3072, SS = 1024LL * 1024;
  const long long HALF = 25165824;  // q->k element stride (8192*3072)
  float* p1 = abuf + 6291456;       // second split-K partial

  prep<<<dim3(2305, 6), blk, 0, stream>>>(Wq, Wk, Wv, W1, Wo, W2, bq, bk, wD, wB, wC, wA, bqk);
  embed_pos_kernel<<<dim3(8192), blk, 0, stream>>>(x, emb, y, yh);

  // q,k = yh @ {Wq,Wk} + {bq,bk}: M=8192 N=3072 K=768 (768 blocks = 3 rounds)
  gemm_nt8<__half, true, false><<<dim3(384, 1, 2), blk8, 0, stream>>>(
      yh, 768, 0, wD, 768, 3072LL * 768, bqk, 3072, qb, 3072, HALF, 12, 768);

  // vT[b][n][s] = sum_k Wv[k][n]*y[b][s][k] + bv[n]  (128^2: 1536 blocks)
  gemm_nt<__half, false, true><<<dim3(192, 1, 8), blk, 0, stream>>>(
      wB, 768, 0, yh, 768, 1024LL * 768, bv, 0, vT, 1024, SH, 8, 768);

  // logits = q k^T (fp32), per batch (128^2: 512 blocks = 1 round @ 2 blk/CU)
  gemm_nt<float, false, false><<<dim3(64, 1, 8), blk, 0, stream>>>(
      qb, 3072, SH, kb, 3072, SH, nullptr, 0, Lg, 1024, SS, 8, 3072);

  softmax_rows<<<dim3(8192), blk, 0, stream>>>(Lg, Ph);  // Ph overlays k (dead)

  // av = P @ V (Bt = v^T), per batch (128^2: 1536 blocks); av overlays q
  gemm_nt<__half, false, false><<<dim3(192, 1, 8), blk, 0, stream>>>(
      Ph, 1024, SS, vT, 1024, SH, nullptr, 0, (__half*)qb, 3072, SH, 24, 1024);

  // a = av @ Wo (split-K=2, 128^2: 768 blocks) -> abuf over vT
  gemm_nt<float, false, false><<<dim3(384, 1, 2), blk, 0, stream>>>(
      (__half*)qb, 3072, 1536, wA, 3072, 1536, nullptr, 0, abuf, 768, 6291456, 6, 1536);

  // y = ln1(y + a + bo)
  residual_stats<false><<<dim3(96, 8), blk, 0, stream>>>(y, abuf, p1, bo, part);
  ln_apply<true><<<dim3(6144), blk, 0, stream>>>(y, yh, ln1w, ln1b, part);

  // f1 = y@W1 + b1 (128^2: 1536 blocks)
  gemm_nt<__half, true, false><<<dim3(1536, 1, 1), blk, 0, stream>>>(
      yh, 768, 0, wC, 768, 0, b1, 0, (__half*)qb, 3072, 0, 24, 768);
  // f = f1@W2 (split-K=2, 128^2: 768 blocks; bias b2 + gelu in residual) -> abuf
  gemm_nt<float, false, false><<<dim3(384, 1, 2), blk, 0, stream>>>(
      (__half*)qb, 3072, 1536, wA + 3072 * 768, 3072, 1536, nullptr, 0, abuf, 768, 6291456, 6, 1536);

  // y = ln2(y + gelu(f + b2))
  residual_stats<true><<<dim3(96, 8), blk, 0, stream>>>(y, abuf, p1, b2, part);
  ln_apply<false><<<dim3(6144), blk, 0, stream>>>(y, nullptr, ln2w, ln2b, part);
}